// Round 10
// baseline (56.283 us; speedup 1.0000x reference)
//
#include <hip/hip_runtime.h>

namespace {
constexpr int kB = 4;
constexpr int kT = 4096;
constexpr int kD = 2048;
constexpr int kBT = 256;             // threads per block (4 waves)
constexpr int kVec = 2;              // channels per thread (float2, 8 B/lane)
constexpr int kL = 256;              // chunk length (output region)
constexpr int kW = 64;               // lookback window (0.9^64 ~ 1.2e-3)
constexpr int kNC = kT / kL;         // 16 chunks per chain
constexpr int kTB = 16;              // timesteps per prefetch tile (16 loads in flight)
constexpr float kMom = 0.1f;
constexpr float kEps = 1e-6f;

typedef float f32x2 __attribute__((ext_vector_type(2)));  // native vec for nontemporal builtin
}

__global__ __launch_bounds__(kBT) void causal_rmsnorm(
    const float* __restrict__ x,
    const float* __restrict__ rs_in,
    const float* __restrict__ wgt,
    float* __restrict__ out,
    float* __restrict__ rs_out)
{
  // each thread owns 2 consecutive channels -> 8 B/lane, 512 B/wave transaction
  const int d = (blockIdx.x * kBT + threadIdx.x) * kVec;
  const int b = blockIdx.y;
  const int c = blockIdx.z;

  const float2 w = *reinterpret_cast<const float2*>(wgt + d);
  const size_t base = (size_t)b * kT * kD + d;
  const float* xp = x + base;
  float* op = out + base;

  const int t0  = c * kL;
  const int tlb = (c == 0) ? 0 : (t0 - kW);
  const int n_all   = (t0 - tlb) + kL;             // 256 (c==0) or 320
  const int n_tiles = n_all / kTB;                 // 16 or 20 (both even)
  const int lb_tiles = (t0 - tlb) / kTB;           // 0 or 4

  float2 rs;
  if (c == 0) {
    rs = *reinterpret_cast<const float2*>(rs_in + b * kD + d);
  } else {
    rs = make_float2(0.f, 0.f);
  }

  float2 bufA[kTB], bufB[kTB];

  auto load_tile = [&](int j, float2* buf) {
    const float* p = xp + (size_t)(tlb + j * kTB) * kD;
    #pragma unroll
    for (int i = 0; i < kTB; ++i)
      buf[i] = *reinterpret_cast<const float2*>(p + (size_t)i * kD);
  };

  auto step_rs = [&](const float2& xv) {
    rs.x = fmaf(1.0f - kMom, rs.x, kMom * xv.x * xv.x);
    rs.y = fmaf(1.0f - kMom, rs.y, kMom * xv.y * xv.y);
  };

  auto compute_tile = [&](int j, const float2* buf) {
    const int tb = tlb + j * kTB;
    if (j >= lb_tiles) {
      float* o = op + (size_t)tb * kD;
      #pragma unroll
      for (int i = 0; i < kTB; ++i) {
        float2 xv = buf[i];
        step_rs(xv);
        f32x2 ov;
        ov.x = xv.x * rsqrtf(rs.x + kEps) * w.x;
        ov.y = xv.y * rsqrtf(rs.y + kEps) * w.y;
        // streaming store: out is write-once, never re-read -> don't pollute L2/L3
        __builtin_nontemporal_store(ov, reinterpret_cast<f32x2*>(o + (size_t)i * kD));
      }
    } else {
      #pragma unroll
      for (int i = 0; i < kTB; ++i) step_rs(buf[i]);
    }
  };

  // double-buffered software pipeline, unrolled by 2 (n_tiles even)
  load_tile(0, bufA);
  for (int j = 0; j < n_tiles; j += 2) {
    load_tile((j + 1 < n_tiles) ? j + 1 : j, bufB);
    compute_tile(j, bufA);
    load_tile((j + 2 < n_tiles) ? j + 2 : n_tiles - 1, bufA);
    compute_tile(j + 1, bufB);
  }

  if (c == kNC - 1) {
    f32x2 rv;
    rv.x = rs.x;
    rv.y = rs.y;
    __builtin_nontemporal_store(rv, reinterpret_cast<f32x2*>(rs_out + b * kD + d));
  }
}

extern "C" void kernel_launch(void* const* d_in, const int* in_sizes, int n_in,
                              void* d_out, int out_size, void* d_ws, size_t ws_size,
                              hipStream_t stream) {
  const float* x   = (const float*)d_in[0];
  const float* rs0 = (const float*)d_in[1];
  const float* wgt = (const float*)d_in[2];
  float* out    = (float*)d_out;
  float* rs_out = out + (size_t)kB * kT * kD;   // rs_final appended after output

  dim3 grid(kD / (kBT * kVec), kB, kNC);        // (4, 4, 16) = 256 blocks, 1024 waves
  causal_rmsnorm<<<grid, dim3(kBT), 0, stream>>>(x, rs0, wgt, out, rs_out);
}

// Round 11
// 51.912 us; speedup vs baseline: 1.0842x; 1.0842x over previous
//
#include <hip/hip_runtime.h>

namespace {
constexpr int kB = 4;
constexpr int kT = 4096;
constexpr int kD = 2048;
constexpr int kBT = 256;             // threads per block (4 waves)
constexpr int kL = 128;              // chunk length — R6-proven geometry (float4 + 1024 waves)
constexpr int kW = 48;               // lookback window (0.9^48 ~ 6.4e-3 rel rs error)
constexpr int kNC = kT / kL;         // 32 chunks per chain
constexpr int kTB = 8;               // timesteps per prefetch tile (8 float4 in flight)
constexpr float kMom = 0.1f;
constexpr float kEps = 1e-6f;
}

__global__ __launch_bounds__(kBT) void causal_rmsnorm(
    const float* __restrict__ x,
    const float* __restrict__ rs_in,
    const float* __restrict__ wgt,
    float* __restrict__ out,
    float* __restrict__ rs_out)
{
  // each thread owns 4 consecutive channels -> 16 B/lane, 1 KB/wave transaction
  const int d = (blockIdx.x * kBT + threadIdx.x) * 4;
  const int b = blockIdx.y;
  const int c = blockIdx.z;

  const float4 w = *reinterpret_cast<const float4*>(wgt + d);
  const size_t base = (size_t)b * kT * kD + d;
  const float* xp = x + base;
  float* op = out + base;

  const int t0  = c * kL;
  const int tlb = (c == 0) ? 0 : (t0 - kW);
  const int n_all   = (t0 - tlb) + kL;             // 128 (c==0) or 176
  const int n_tiles = n_all / kTB;                 // 16 or 22 (both even)
  const int lb_tiles = (t0 - tlb) / kTB;           // 0 or 6

  float4 rs;
  if (c == 0) {
    rs = *reinterpret_cast<const float4*>(rs_in + b * kD + d);
  } else {
    rs = make_float4(0.f, 0.f, 0.f, 0.f);
  }

  float4 bufA[kTB], bufB[kTB];

  auto load_tile = [&](int j, float4* buf) {
    const float* p = xp + (size_t)(tlb + j * kTB) * kD;
    #pragma unroll
    for (int i = 0; i < kTB; ++i)
      buf[i] = *reinterpret_cast<const float4*>(p + (size_t)i * kD);
  };

  auto step_rs = [&](const float4& xv) {
    rs.x = fmaf(1.0f - kMom, rs.x, kMom * xv.x * xv.x);
    rs.y = fmaf(1.0f - kMom, rs.y, kMom * xv.y * xv.y);
    rs.z = fmaf(1.0f - kMom, rs.z, kMom * xv.z * xv.z);
    rs.w = fmaf(1.0f - kMom, rs.w, kMom * xv.w * xv.w);
  };

  auto compute_tile = [&](int j, const float4* buf) {
    const int tb = tlb + j * kTB;
    if (j >= lb_tiles) {
      float* o = op + (size_t)tb * kD;
      #pragma unroll
      for (int i = 0; i < kTB; ++i) {
        float4 xv = buf[i];
        step_rs(xv);
        float4 ov;
        ov.x = xv.x * rsqrtf(rs.x + kEps) * w.x;
        ov.y = xv.y * rsqrtf(rs.y + kEps) * w.y;
        ov.z = xv.z * rsqrtf(rs.z + kEps) * w.z;
        ov.w = xv.w * rsqrtf(rs.w + kEps) * w.w;
        *reinterpret_cast<float4*>(o + (size_t)i * kD) = ov;
      }
    } else {
      #pragma unroll
      for (int i = 0; i < kTB; ++i) step_rs(buf[i]);
    }
  };

  // double-buffered software pipeline, unrolled by 2 (n_tiles even)
  load_tile(0, bufA);
  for (int j = 0; j < n_tiles; j += 2) {
    load_tile((j + 1 < n_tiles) ? j + 1 : j, bufB);
    compute_tile(j, bufA);
    load_tile((j + 2 < n_tiles) ? j + 2 : n_tiles - 1, bufA);
    compute_tile(j + 1, bufB);
  }

  if (c == kNC - 1)
    *reinterpret_cast<float4*>(rs_out + b * kD + d) = rs;
}

extern "C" void kernel_launch(void* const* d_in, const int* in_sizes, int n_in,
                              void* d_out, int out_size, void* d_ws, size_t ws_size,
                              hipStream_t stream) {
  const float* x   = (const float*)d_in[0];
  const float* rs0 = (const float*)d_in[1];
  const float* wgt = (const float*)d_in[2];
  float* out    = (float*)d_out;
  float* rs_out = out + (size_t)kB * kT * kD;   // rs_final appended after output

  dim3 grid(kD / (kBT * 4), kB, kNC);           // (2, 4, 32) = 256 blocks, 1024 waves
  causal_rmsnorm<<<grid, dim3(kBT), 0, stream>>>(x, rs0, wgt, out, rs_out);
}